// Round 6
// baseline (95.064 us; speedup 1.0000x reference)
//
#include <hip/hip_runtime.h>

// DIN attention pooling — round 6: wave-per-(b,half), zero block barriers.
//   Wb[e][h] = (W1b-W1c)[e][h] + q_e*W1d[e][h];  qh[h] = b1[h] + q @ (W1a+W1c)
//   H = sig(K@Wb + qh); G = sig(H@W2 + b2); s = G@W3 + b3 (masked); out = s^T K
// Keys live only in MFMA A-fragments (no LDS staging); weights pre-transposed
// to f16 fragment layout in __device__ globals by a prep kernel; per-wave LDS
// slabs only for the 16x16 C->A transposes. Halves merge via atomicAdd.
// R6 fix: slabs zero-initialized + overhang-padded (reads of K-padding cols
// hit zeros, never garbage LDS -> no NaN*0 in MFMA).

constexpr int Bn = 2048, Tn = 200, En = 64;
constexpr int HS_W = 84;     // H slab stride (f16)
constexpr int GS_W = 52;     // G slab stride
constexpr int HSLAB = 16 * HS_W + 16;  // 1360 f16 (covers row-15 read overhang to col 95)
constexpr int GSLAB = 16 * GS_W + 16;  // 848 f16  (covers row-15 read overhang to col 63)

typedef _Float16 f16;
typedef _Float16 f16x8 __attribute__((ext_vector_type(8)));
typedef float f32x4 __attribute__((ext_vector_type(4)));

__device__ __align__(16) f16 g_wkf[80 * 64];    // [h][e]  W1b - W1c
__device__ __align__(16) f16 g_wqf[80 * 64];    // [h][e]  W1d
__device__ __align__(16) f16 g_wsumT[80 * 64];  // [h][e]  W1a + W1c
__device__ __align__(16) f16 g_w2t[48 * 96];    // [j][h]  W2^T, zeros j>=40 or h>=80
__device__ __align__(16) f16 g_w3[64];          // [j]     W3, zeros j>=40

__device__ __forceinline__ float fsig(float x) {
  return __fdividef(1.0f, 1.0f + __expf(-x));
}

__global__ __launch_bounds__(256) void din_prep(const float* __restrict__ W1,
                                                const float* __restrict__ W2,
                                                const float* __restrict__ W3) {
  int idx = blockIdx.x * 256 + threadIdx.x;   // grid 20 -> 5120
  if (idx < 5120) {
    int h = idx >> 6, e = idx & 63;
    float wa = W1[e * 80 + h], wb = W1[(64 + e) * 80 + h];
    float wc = W1[(128 + e) * 80 + h], wd = W1[(192 + e) * 80 + h];
    g_wkf[idx] = (f16)(wb - wc);
    g_wqf[idx] = (f16)wd;
    g_wsumT[idx] = (f16)(wa + wc);
  }
  if (idx < 4608) {
    int j = idx / 96, h = idx - j * 96;
    g_w2t[idx] = (h < 80 && j < 40) ? (f16)W2[h * 40 + j] : (f16)0.0f;
  }
  if (idx < 64) g_w3[idx] = (idx < 40) ? (f16)W3[idx] : (f16)0.0f;
}

__global__ __launch_bounds__(256, 4) void din_main(
    const float* __restrict__ query,
    const float* __restrict__ keys,
    const int*   __restrict__ keys_length,
    const float* __restrict__ b1,
    const float* __restrict__ b2,
    const float* __restrict__ b3,
    float* __restrict__ out)
{
  __shared__ __align__(16) f16 sH[4][HSLAB];   // 10,880 B
  __shared__ __align__(16) f16 sG[4][GSLAB];   //  6,784 B
  __shared__ float sSw[4][16];                 //    256 B

  const int tid = threadIdx.x;
  const int lane = tid & 63;
  const int wid = tid >> 6;
  const int l15 = lane & 15;
  const int l4  = lane >> 4;

  const int b    = blockIdx.x * 2 + (wid >> 1);
  const int half = wid & 1;
  const int mt0  = half ? 7 : 0;
  const int mt1  = half ? 13 : 7;

  const float* qp = query + (size_t)b * En;
  const float* kb = keys + (size_t)b * Tn * En;
  const int len = keys_length[b];
  const float b3v = b3[0];

  f16* hs = sH[wid];
  f16* gs = sG[wid];

  // ---- zero own slabs (main loop never writes cols >=80 / >=48; the padded
  //      K-columns read by L2/L3 MFMAs must be 0.0, not garbage) ----
  const f16x8 zf = (f16x8)(f16)0.0f;
  for (int i = lane * 8; i < HSLAB; i += 64 * 8) *(f16x8*)&hs[i] = zf;
  for (int i = lane * 8; i < GSLAB; i += 64 * 8) *(f16x8*)&gs[i] = zf;

  // ---- q fragments (f16), and row-0-only copies for the qh matvec MFMA ----
  f16x8 qf0, qf1;
  {
    float4 qa = *(const float4*)(qp + l4 * 8);
    float4 qb = *(const float4*)(qp + l4 * 8 + 4);
    float4 qc = *(const float4*)(qp + 32 + l4 * 8);
    float4 qd = *(const float4*)(qp + 32 + l4 * 8 + 4);
    qf0 = (f16x8){(f16)qa.x,(f16)qa.y,(f16)qa.z,(f16)qa.w,
                  (f16)qb.x,(f16)qb.y,(f16)qb.z,(f16)qb.w};
    qf1 = (f16x8){(f16)qc.x,(f16)qc.y,(f16)qc.z,(f16)qc.w,
                  (f16)qd.x,(f16)qd.y,(f16)qd.z,(f16)qd.w};
  }
  f16x8 qz0 = (l15 == 0) ? qf0 : zf;
  f16x8 qz1 = (l15 == 0) ? qf1 : zf;

  // ---- qh[c] via 1-row MFMA: qh = b1 + q @ wsum  (c = n*16+l15) ----
  float qhv[5];
  #pragma unroll
  for (int n = 0; n < 5; ++n) {
    int c = n * 16 + l15;
    f16x8 bs0 = *(const f16x8*)&g_wsumT[c * 64 + l4 * 8];
    f16x8 bs1 = *(const f16x8*)&g_wsumT[c * 64 + 32 + l4 * 8];
    f32x4 acc = {0.f, 0.f, 0.f, 0.f};
    acc = __builtin_amdgcn_mfma_f32_16x16x32_f16(qz0, bs0, acc, 0, 0, 0);
    acc = __builtin_amdgcn_mfma_f32_16x16x32_f16(qz1, bs1, acc, 0, 0, 0);
    qhv[n] = __shfl(acc[0], l15, 64) + b1[c];
  }

  // ---- L1 B-fragments: Wb = wk + q*wqk (elementwise f16) ----
  f16x8 bf0[5], bf1[5];
  #pragma unroll
  for (int n = 0; n < 5; ++n) {
    int c = n * 16 + l15;
    f16x8 wk0 = *(const f16x8*)&g_wkf[c * 64 + l4 * 8];
    f16x8 wq0 = *(const f16x8*)&g_wqf[c * 64 + l4 * 8];
    f16x8 wk1 = *(const f16x8*)&g_wkf[c * 64 + 32 + l4 * 8];
    f16x8 wq1 = *(const f16x8*)&g_wqf[c * 64 + 32 + l4 * 8];
    bf0[n] = wk0 + qf0 * wq0;
    bf1[n] = wk1 + qf1 * wq1;
  }

  // ---- L3 B-fragment (broadcast across cols) ----
  f16x8 w3f0 = *(const f16x8*)&g_w3[l4 * 8];
  f16x8 w3f1 = *(const f16x8*)&g_w3[32 + l4 * 8];

  // ---- layer-2 bias (per col c = n*16+l15, zeros past 40) ----
  float b2v[3];
  #pragma unroll
  for (int n = 0; n < 3; ++n) {
    int c = n * 16 + l15;
    b2v[n] = (c < 40) ? b2[c] : 0.0f;
  }

  float poolA[8] = {0,0,0,0,0,0,0,0};
  float poolB[8] = {0,0,0,0,0,0,0,0};

  // ---- prefetch first tile's keys rows ----
  float4 p0, p1, p2, p3;
  {
    int r = mt0 * 16 + l15; int rc = r < Tn ? r : Tn - 1;
    const float* kr = kb + rc * 64;
    p0 = *(const float4*)(kr + l4 * 8);
    p1 = *(const float4*)(kr + l4 * 8 + 4);
    p2 = *(const float4*)(kr + 32 + l4 * 8);
    p3 = *(const float4*)(kr + 32 + l4 * 8 + 4);
  }

  for (int mt = mt0; mt < mt1; ++mt) {
    // current tile A-frags from prefetched registers
    f16x8 ka = (f16x8){(f16)p0.x,(f16)p0.y,(f16)p0.z,(f16)p0.w,
                       (f16)p1.x,(f16)p1.y,(f16)p1.z,(f16)p1.w};
    f16x8 kc = (f16x8){(f16)p2.x,(f16)p2.y,(f16)p2.z,(f16)p2.w,
                       (f16)p3.x,(f16)p3.y,(f16)p3.z,(f16)p3.w};
    // issue next tile's loads early
    if (mt + 1 < mt1) {
      int r = (mt + 1) * 16 + l15; int rc = r < Tn ? r : Tn - 1;
      const float* kr = kb + rc * 64;
      p0 = *(const float4*)(kr + l4 * 8);
      p1 = *(const float4*)(kr + l4 * 8 + 4);
      p2 = *(const float4*)(kr + 32 + l4 * 8);
      p3 = *(const float4*)(kr + 32 + l4 * 8 + 4);
    }

    // L1: accH = K_tile @ Wb
    float accH[5][4];
    #pragma unroll
    for (int n = 0; n < 5; ++n) {
      f32x4 acc = {0.f, 0.f, 0.f, 0.f};
      acc = __builtin_amdgcn_mfma_f32_16x16x32_f16(ka, bf0[n], acc, 0, 0, 0);
      acc = __builtin_amdgcn_mfma_f32_16x16x32_f16(kc, bf1[n], acc, 0, 0, 0);
      #pragma unroll
      for (int i = 0; i < 4; ++i) accH[n][i] = acc[i];
    }
    // H transpose slab (sigmoid); only cols 0..79 written, cols 80..95 stay 0
    #pragma unroll
    for (int n = 0; n < 5; ++n) {
      int c = n * 16 + l15;
      #pragma unroll
      for (int i = 0; i < 4; ++i)
        hs[(l4 * 4 + i) * HS_W + c] = (f16)fsig(accH[n][i] + qhv[n]);
    }
    f16x8 aH[3];
    #pragma unroll
    for (int ks = 0; ks < 3; ++ks)
      aH[ks] = *(const f16x8*)&hs[l15 * HS_W + ks * 32 + l4 * 8];

    // L2: accG = H @ W2 (B-frags from L1-hot global)
    float accG[3][4];
    #pragma unroll
    for (int n = 0; n < 3; ++n) {
      int c = n * 16 + l15;
      f32x4 acc = {0.f, 0.f, 0.f, 0.f};
      #pragma unroll
      for (int ks = 0; ks < 3; ++ks) {
        f16x8 bw = *(const f16x8*)&g_w2t[c * 96 + ks * 32 + l4 * 8];
        acc = __builtin_amdgcn_mfma_f32_16x16x32_f16(aH[ks], bw, acc, 0, 0, 0);
      }
      #pragma unroll
      for (int i = 0; i < 4; ++i) accG[n][i] = acc[i];
    }
    // G transpose slab (sigmoid); only cols 0..47 written, cols 48..63 stay 0
    #pragma unroll
    for (int n = 0; n < 3; ++n) {
      int c = n * 16 + l15;
      #pragma unroll
      for (int i = 0; i < 4; ++i)
        gs[(l4 * 4 + i) * GS_W + c] = (f16)fsig(accG[n][i] + b2v[n]);
    }

    // L3: scores (all cols identical: W3 broadcast row)
    {
      f32x4 acc = {0.f, 0.f, 0.f, 0.f};
      f16x8 aG0 = *(const f16x8*)&gs[l15 * GS_W + l4 * 8];
      f16x8 aG1 = *(const f16x8*)&gs[l15 * GS_W + 32 + l4 * 8];
      acc = __builtin_amdgcn_mfma_f32_16x16x32_f16(aG0, w3f0, acc, 0, 0, 0);
      acc = __builtin_amdgcn_mfma_f32_16x16x32_f16(aG1, w3f1, acc, 0, 0, 0);
      if (l15 == 0) {
        #pragma unroll
        for (int i = 0; i < 4; ++i) {
          int rr = mt * 16 + l4 * 4 + i;
          sSw[wid][l4 * 4 + i] = (rr < len) ? acc[i] + b3v : 0.0f;
        }
      }
    }
    // broadcast score for this lane's row; pool with live A-frags
    float sv = sSw[wid][l15];
    #pragma unroll
    for (int j = 0; j < 8; ++j) {
      poolA[j] += sv * (float)ka[j];
      poolB[j] += sv * (float)kc[j];
    }
  }

  // ---- reduce pooling over the 16 rows (l15) of each l4 group ----
  #pragma unroll
  for (int m = 1; m < 16; m <<= 1) {
    #pragma unroll
    for (int j = 0; j < 8; ++j) {
      poolA[j] += __shfl_xor(poolA[j], m, 64);
      poolB[j] += __shfl_xor(poolB[j], m, 64);
    }
  }
  if (l15 == 0) {
    float* ob = out + (size_t)b * En;
    #pragma unroll
    for (int j = 0; j < 8; ++j) {
      atomicAdd(&ob[l4 * 8 + j], poolA[j]);
      atomicAdd(&ob[32 + l4 * 8 + j], poolB[j]);
    }
  }
}

extern "C" void kernel_launch(void* const* d_in, const int* in_sizes, int n_in,
                              void* d_out, int out_size, void* d_ws, size_t ws_size,
                              hipStream_t stream) {
  const float* query       = (const float*)d_in[0];
  const float* keys        = (const float*)d_in[1];
  const int*   keys_length = (const int*)d_in[2];
  const float* W1 = (const float*)d_in[3];
  const float* b1 = (const float*)d_in[4];
  const float* W2 = (const float*)d_in[5];
  const float* b2 = (const float*)d_in[6];
  const float* W3 = (const float*)d_in[7];
  const float* b3 = (const float*)d_in[8];
  float* out = (float*)d_out;

  hipMemsetAsync(out, 0, (size_t)Bn * En * sizeof(float), stream);
  hipLaunchKernelGGL(din_prep, dim3(20), dim3(256), 0, stream, W1, W2, W3);
  hipLaunchKernelGGL(din_main, dim3(Bn / 2), dim3(256), 0, stream,
                     query, keys, keys_length, b1, b2, b3, out);
}

// Round 7
// 70.319 us; speedup vs baseline: 1.3519x; 1.3519x over previous
//
#include <hip/hip_runtime.h>

// DIN attention pooling — round 7: wave-per-(b,half), zero block barriers,
// register-budget fixed (R6 spilled: VGPR capped 64, 57MB scratch writes).
//   Wb[e][h] = (W1b-W1c)[e][h] + q_e*W1d[e][h];  qh[h] = b1[h] + q @ (W1a+W1c)
//   H = sig(K@Wb + qh); G = sig(H@W2 + b2); s = G@W3 + b3 (masked); out = s^T K
// R7: no G slab / no L3 MFMA (VALU dot + shfl reduce), qh via VALU dot,
// no pinned prefetch regs, sigmoid folded per-n. Only LDS: H transpose slab.

constexpr int Bn = 2048, Tn = 200, En = 64;
constexpr int HS_W = 84;               // H slab stride (f16): conflict-free
constexpr int HSLAB = 16 * HS_W + 16;  // 1360 f16 covers row-15 read overhang

typedef _Float16 f16;
typedef _Float16 f16x8 __attribute__((ext_vector_type(8)));
typedef float f32x4 __attribute__((ext_vector_type(4)));

__device__ __align__(16) f16 g_wkf[80 * 64];    // [h][e]  W1b - W1c
__device__ __align__(16) f16 g_wqf[80 * 64];    // [h][e]  W1d
__device__ __align__(16) f16 g_wsumT[80 * 64];  // [h][e]  W1a + W1c
__device__ __align__(16) f16 g_w2t[48 * 96];    // [j][h]  W2^T, zeros j>=40 or h>=80

__device__ __forceinline__ float fsig(float x) {
  return __fdividef(1.0f, 1.0f + __expf(-x));
}

__global__ __launch_bounds__(256) void din_prep(const float* __restrict__ W1,
                                                const float* __restrict__ W2) {
  int idx = blockIdx.x * 256 + threadIdx.x;   // grid 20 -> 5120
  if (idx < 5120) {
    int h = idx >> 6, e = idx & 63;
    float wa = W1[e * 80 + h], wb = W1[(64 + e) * 80 + h];
    float wc = W1[(128 + e) * 80 + h], wd = W1[(192 + e) * 80 + h];
    g_wkf[idx] = (f16)(wb - wc);
    g_wqf[idx] = (f16)wd;
    g_wsumT[idx] = (f16)(wa + wc);
  }
  if (idx < 4608) {
    int j = idx / 96, h = idx - j * 96;
    g_w2t[idx] = (h < 80 && j < 40) ? (f16)W2[h * 40 + j] : (f16)0.0f;
  }
}

__global__ __launch_bounds__(256, 3) void din_main(
    const float* __restrict__ query,
    const float* __restrict__ keys,
    const int*   __restrict__ keys_length,
    const float* __restrict__ b1,
    const float* __restrict__ b2,
    const float* __restrict__ W3,
    const float* __restrict__ b3,
    float* __restrict__ out)
{
  __shared__ __align__(16) f16 sH[4][HSLAB];   // 10,880 B
  __shared__ float sSw[4][16];                 //    256 B

  const int tid = threadIdx.x;
  const int lane = tid & 63;
  const int wid = tid >> 6;
  const int l15 = lane & 15;
  const int l4  = lane >> 4;

  const int b    = blockIdx.x * 2 + (wid >> 1);
  const int half = wid & 1;
  const int mt0  = half ? 7 : 0;
  const int mt1  = half ? 13 : 7;

  const float* qp = query + (size_t)b * En;
  const float* kb = keys + (size_t)b * Tn * En;
  const int len = keys_length[b];
  const float b3v = b3[0];

  f16* hs = sH[wid];

  // ---- zero own H slab once (cols 80..95 = L2 K-padding must be 0.0) ----
  const f16x8 zf = (f16x8)(f16)0.0f;
  for (int i = lane * 8; i < HSLAB; i += 64 * 8) *(f16x8*)&hs[i] = zf;

  // ---- q fragments (f16) ----
  f16x8 qf0, qf1;
  {
    float4 qa = *(const float4*)(qp + l4 * 8);
    float4 qb = *(const float4*)(qp + l4 * 8 + 4);
    float4 qc = *(const float4*)(qp + 32 + l4 * 8);
    float4 qd = *(const float4*)(qp + 32 + l4 * 8 + 4);
    qf0 = (f16x8){(f16)qa.x,(f16)qa.y,(f16)qa.z,(f16)qa.w,
                  (f16)qb.x,(f16)qb.y,(f16)qb.z,(f16)qb.w};
    qf1 = (f16x8){(f16)qc.x,(f16)qc.y,(f16)qc.z,(f16)qc.w,
                  (f16)qd.x,(f16)qd.y,(f16)qd.z,(f16)qd.w};
  }

  // ---- qh[c] = b1[c] + q @ wsum[:,c] via VALU dot + shfl over l4 ----
  float qhv[5];
  #pragma unroll
  for (int n = 0; n < 5; ++n) {
    int c = n * 16 + l15;
    f16x8 ws0 = *(const f16x8*)&g_wsumT[c * 64 + l4 * 8];
    f16x8 ws1 = *(const f16x8*)&g_wsumT[c * 64 + 32 + l4 * 8];
    float p = 0.f;
    #pragma unroll
    for (int j = 0; j < 8; ++j)
      p += (float)qf0[j] * (float)ws0[j] + (float)qf1[j] * (float)ws1[j];
    p += __shfl_xor(p, 16, 64);
    p += __shfl_xor(p, 32, 64);
    qhv[n] = p + b1[c];
  }

  // ---- L1 B-fragments: Wb = wk + q*wqk (elementwise f16) ----
  f16x8 bf0[5], bf1[5];
  #pragma unroll
  for (int n = 0; n < 5; ++n) {
    int c = n * 16 + l15;
    bf0[n] = *(const f16x8*)&g_wkf[c * 64 + l4 * 8]
           + qf0 * *(const f16x8*)&g_wqf[c * 64 + l4 * 8];
    bf1[n] = *(const f16x8*)&g_wkf[c * 64 + 32 + l4 * 8]
           + qf1 * *(const f16x8*)&g_wqf[c * 64 + 32 + l4 * 8];
  }

  // ---- per-col constants for L2/L3 ----
  float b2v[3], w3v[3];
  #pragma unroll
  for (int n = 0; n < 3; ++n) {
    int c = n * 16 + l15;
    b2v[n] = (c < 40) ? b2[c] : 0.0f;
    w3v[n] = (c < 40) ? W3[c] : 0.0f;
  }

  float poolA[8] = {0,0,0,0,0,0,0,0};
  float poolB[8] = {0,0,0,0,0,0,0,0};

  for (int mt = mt0; mt < mt1; ++mt) {
    // keys rows -> A-frags (row = l15, cols l4*8..; two 32-col halves)
    int r = mt * 16 + l15; int rc = r < Tn ? r : Tn - 1;
    const float* kr = kb + rc * 64;
    float4 p0 = *(const float4*)(kr + l4 * 8);
    float4 p1 = *(const float4*)(kr + l4 * 8 + 4);
    float4 p2 = *(const float4*)(kr + 32 + l4 * 8);
    float4 p3 = *(const float4*)(kr + 32 + l4 * 8 + 4);
    f16x8 ka = (f16x8){(f16)p0.x,(f16)p0.y,(f16)p0.z,(f16)p0.w,
                       (f16)p1.x,(f16)p1.y,(f16)p1.z,(f16)p1.w};
    f16x8 kc = (f16x8){(f16)p2.x,(f16)p2.y,(f16)p2.z,(f16)p2.w,
                       (f16)p3.x,(f16)p3.y,(f16)p3.z,(f16)p3.w};

    // L1 + sigmoid -> H slab, per n (accH liveness = 4)
    #pragma unroll
    for (int n = 0; n < 5; ++n) {
      f32x4 acc = {0.f, 0.f, 0.f, 0.f};
      acc = __builtin_amdgcn_mfma_f32_16x16x32_f16(ka, bf0[n], acc, 0, 0, 0);
      acc = __builtin_amdgcn_mfma_f32_16x16x32_f16(kc, bf1[n], acc, 0, 0, 0);
      int c = n * 16 + l15;
      #pragma unroll
      for (int i = 0; i < 4; ++i)
        hs[(l4 * 4 + i) * HS_W + c] = (f16)fsig(acc[i] + qhv[n]);
    }
    // H^T A-frags (row = l15, k-cols l4*8.. within 96)
    f16x8 aH0 = *(const f16x8*)&hs[l15 * HS_W + l4 * 8];
    f16x8 aH1 = *(const f16x8*)&hs[l15 * HS_W + 32 + l4 * 8];
    f16x8 aH2 = *(const f16x8*)&hs[l15 * HS_W + 64 + l4 * 8];

    // L2 + sigmoid + W3 dot (no G slab, no L3 MFMA)
    float sc[4] = {0.f, 0.f, 0.f, 0.f};
    #pragma unroll
    for (int n = 0; n < 3; ++n) {
      int c = n * 16 + l15;
      f32x4 acc = {0.f, 0.f, 0.f, 0.f};
      acc = __builtin_amdgcn_mfma_f32_16x16x32_f16(aH0, *(const f16x8*)&g_w2t[c * 96 + l4 * 8], acc, 0, 0, 0);
      acc = __builtin_amdgcn_mfma_f32_16x16x32_f16(aH1, *(const f16x8*)&g_w2t[c * 96 + 32 + l4 * 8], acc, 0, 0, 0);
      acc = __builtin_amdgcn_mfma_f32_16x16x32_f16(aH2, *(const f16x8*)&g_w2t[c * 96 + 64 + l4 * 8], acc, 0, 0, 0);
      #pragma unroll
      for (int i = 0; i < 4; ++i)
        sc[i] += fsig(acc[i] + b2v[n]) * w3v[n];
    }
    // reduce score over the 16 cols held across l15 (lane bits 0..3)
    #pragma unroll
    for (int m = 1; m < 16; m <<= 1) {
      #pragma unroll
      for (int i = 0; i < 4; ++i) sc[i] += __shfl_xor(sc[i], m, 64);
    }
    if (l15 == 0) {
      #pragma unroll
      for (int i = 0; i < 4; ++i) {
        int rr = mt * 16 + l4 * 4 + i;
        sSw[wid][l4 * 4 + i] = (rr < len) ? sc[i] + b3v : 0.0f;
      }
    }
    // broadcast this lane's row score (same-wave LDS; no barrier needed)
    float sv = sSw[wid][l15];
    #pragma unroll
    for (int j = 0; j < 8; ++j) {
      poolA[j] += sv * (float)ka[j];
      poolB[j] += sv * (float)kc[j];
    }
  }

  // ---- reduce pooling over the 16 rows (l15) of each l4 group ----
  #pragma unroll
  for (int m = 1; m < 16; m <<= 1) {
    #pragma unroll
    for (int j = 0; j < 8; ++j) {
      poolA[j] += __shfl_xor(poolA[j], m, 64);
      poolB[j] += __shfl_xor(poolB[j], m, 64);
    }
  }
  if (l15 == 0) {
    float* ob = out + (size_t)b * En;
    #pragma unroll
    for (int j = 0; j < 8; ++j) {
      atomicAdd(&ob[l4 * 8 + j], poolA[j]);
      atomicAdd(&ob[32 + l4 * 8 + j], poolB[j]);
    }
  }
}

extern "C" void kernel_launch(void* const* d_in, const int* in_sizes, int n_in,
                              void* d_out, int out_size, void* d_ws, size_t ws_size,
                              hipStream_t stream) {
  const float* query       = (const float*)d_in[0];
  const float* keys        = (const float*)d_in[1];
  const int*   keys_length = (const int*)d_in[2];
  const float* W1 = (const float*)d_in[3];
  const float* b1 = (const float*)d_in[4];
  const float* W2 = (const float*)d_in[5];
  const float* b2 = (const float*)d_in[6];
  const float* W3 = (const float*)d_in[7];
  const float* b3 = (const float*)d_in[8];
  float* out = (float*)d_out;

  hipMemsetAsync(out, 0, (size_t)Bn * En * sizeof(float), stream);
  hipLaunchKernelGGL(din_prep, dim3(20), dim3(256), 0, stream, W1, W2);
  hipLaunchKernelGGL(din_main, dim3(Bn / 2), dim3(256), 0, stream,
                     query, keys, keys_length, b1, b2, W3, b3, out);
}